// Round 3
// baseline (248.466 us; speedup 1.0000x reference)
//
#include <hip/hip_runtime.h>

#define EPS 1e-4f

constexpr int B = 2048;
constexpr int D = 3706;              // even: element pairs never straddle rows
constexpr int NE = B * D;            // 7,589,888 elements
constexpr int NQ = NE / 4;           // 1,897,472 quads = 7412 * 256 exactly
constexpr int BLK = 256;
constexpr int GRID = NQ / BLK;       // 7412, exact (no tail)

// Native clang vector type: required by __builtin_nontemporal_{load,store}
// (HIP's float4 is a class and is rejected by the builtin).
typedef float v4f __attribute__((ext_vector_type(4)));

// Per-element bucketize. Boundaries are computed in the reference's exact
// fp32 order: step_k = max(L_k,0) + EPS first, then sequential cumsum adds.
__device__ __forceinline__ void bucketize(float a, float mb, float4 L,
                                          float* __restrict__ r6, float& v) {
    const float s0 = fmaxf(L.x, 0.0f) + EPS;
    const float s1 = fmaxf(L.y, 0.0f) + EPS;
    const float s2 = fmaxf(L.z, 0.0f) + EPS;
    const float s3 = fmaxf(L.w, 0.0f) + EPS;
    const float b0 = mb;
    const float b1 = b0 + s0;
    const float b2 = b1 + s1;
    const float b3 = b2 + s2;
    const float b4 = b3 + s3;

    // b is strictly increasing (steps >= EPS > 0), so {k : a > b_k} is a prefix.
    const int cnt = (int)(a > b0) + (int)(a > b1) + (int)(a > b2)
                  + (int)(a > b3) + (int)(a > b4);
    // heaviside(0)=0: if a equals any boundary, every dist entry is 0.
    const bool eq = (a == b0) | (a == b1) | (a == b2) | (a == b3) | (a == b4);
    const float ok = eq ? 0.0f : 1.0f;

#pragma unroll
    for (int r = 0; r < 6; ++r) r6[r] = (r == cnt) ? ok : 0.0f;
    v = eq ? 0.0f : (float)cnt;
}

__global__ __launch_bounds__(256) void disc_kernel(
        const float* __restrict__ fake,
        const float* __restrict__ minb,
        const float* __restrict__ lens,
        float* __restrict__ out) {
    // Staging: 1024 elements * 6 floats = 6144 floats = 1536 v4f = 24 KB.
    // Transposed layout sd[k*BLK + t]: write side is 16B lane stride
    // (conflict-free); read side aliases at most 1.5x. -> 6 blocks/CU by LDS.
    __shared__ v4f sd[6 * BLK];

    const int t = threadIdx.x;
    const int q = blockIdx.x * BLK + t;      // quad index (grid exact)
    const int flat = q * 4;                  // first element of the quad
    const int c0 = flat % D;                 // even column
    int c2 = c0 + 2;                         // quad may straddle a row:
    if (c2 == D) c2 = 0;                     // D % 4 == 2, so wrap is to col 0

    const v4f a = __builtin_nontemporal_load(
        reinterpret_cast<const v4f*>(fake) + q);
    const float2 mb01 = *reinterpret_cast<const float2*>(minb + c0);
    const float2 mb23 = *reinterpret_cast<const float2*>(minb + c2);
    const float4 L0 = reinterpret_cast<const float4*>(lens)[c0];
    const float4 L1 = reinterpret_cast<const float4*>(lens)[c0 + 1];
    const float4 L2 = reinterpret_cast<const float4*>(lens)[c2];
    const float4 L3 = reinterpret_cast<const float4*>(lens)[c2 + 1];

    float r0[6], r1[6], r2[6], r3[6], v0, v1, v2, v3;
    bucketize(a.x, mb01.x, L0, r0, v0);
    bucketize(a.y, mb01.y, L1, r1, v1);
    bucketize(a.z, mb23.x, L2, r2, v2);
    bucketize(a.w, mb23.y, L3, r3, v3);

    // 24 dist floats -> 6 v4f quarters, stored transposed.
    sd[0 * BLK + t] = (v4f){r0[0], r0[1], r0[2], r0[3]};
    sd[1 * BLK + t] = (v4f){r0[4], r0[5], r1[0], r1[1]};
    sd[2 * BLK + t] = (v4f){r1[2], r1[3], r1[4], r1[5]};
    sd[3 * BLK + t] = (v4f){r2[0], r2[1], r2[2], r2[3]};
    sd[4 * BLK + t] = (v4f){r2[4], r2[5], r3[0], r3[1]};
    sd[5 * BLK + t] = (v4f){r3[2], r3[3], r3[4], r3[5]};

    // val: 16B/lane, consecutive lanes -> consecutive addresses. Issue before
    // the barrier so it overlaps the LDS round-trip. Nontemporal: write-once.
    v4f* val4 = reinterpret_cast<v4f*>(out + (size_t)NE * 6);
    __builtin_nontemporal_store((v4f){v0, v1, v2, v3}, val4 + q);

    __syncthreads();

    // Block's dist region = 1536 consecutive v4f at dp = out4 + blockIdx*1536.
    // Thread t writes logical v4f indices {t, t+256, ..., t+1280}:
    // fully coalesced 16B/lane streams. Logical index j belongs to source
    // thread j/6, quarter j%6, stored at sd[(j%6)*BLK + j/6].
    v4f* dp = reinterpret_cast<v4f*>(out) + (size_t)blockIdx.x * (6 * BLK);
#pragma unroll
    for (int m = 0; m < 6; ++m) {
        const int j = m * BLK + t;
        const int src = j / 6;               // div by constant -> mulhi+shift
        const int k = j - src * 6;
        __builtin_nontemporal_store(sd[k * BLK + src], dp + j);
    }
}

extern "C" void kernel_launch(void* const* d_in, const int* in_sizes, int n_in,
                              void* d_out, int out_size, void* d_ws, size_t ws_size,
                              hipStream_t stream) {
    const float* fake = (const float*)d_in[0];   // [B, D]
    const float* minb = (const float*)d_in[1];   // [D]
    const float* lens = (const float*)d_in[2];   // [D, 4]
    float* out = (float*)d_out;                  // dist [B,D,6] then val [B,D]

    disc_kernel<<<GRID, BLK, 0, stream>>>(fake, minb, lens, out);
}

// Round 4
// 247.399 us; speedup vs baseline: 1.0043x; 1.0043x over previous
//
#include <hip/hip_runtime.h>

#define EPS 1e-4f

// Native clang vector types (also required by any nontemporal builtins;
// HIP's float2/float4 classes are rejected there).
typedef float v2f __attribute__((ext_vector_type(2)));
typedef float v4f __attribute__((ext_vector_type(4)));

constexpr int B = 2048;
constexpr int D = 3706;              // even: pairs never straddle rows
constexpr int NE = B * D;            // 7,589,888 elements
constexpr int NP = NE / 2;           // 3,794,944 pairs
constexpr int BLK = 256;
constexpr int NTILES = NP / BLK;     // 14824 tiles of 256 pairs (exact)
constexpr int GRIDB = 1536;          // persistent: 6 blocks/CU x 256 CUs

// Per-element bucketize. Boundaries are computed in the reference's exact
// fp32 order: step_k = max(L_k,0) + EPS first, then sequential cumsum adds.
__device__ __forceinline__ void bucketize(float a, float mb, v4f L,
                                          float* __restrict__ r6, float& v) {
    const float s0 = fmaxf(L.x, 0.0f) + EPS;
    const float s1 = fmaxf(L.y, 0.0f) + EPS;
    const float s2 = fmaxf(L.z, 0.0f) + EPS;
    const float s3 = fmaxf(L.w, 0.0f) + EPS;
    const float b0 = mb;
    const float b1 = b0 + s0;
    const float b2 = b1 + s1;
    const float b3 = b2 + s2;
    const float b4 = b3 + s3;

    // b is strictly increasing (steps >= EPS > 0), so {k : a > b_k} is a prefix.
    const int cnt = (int)(a > b0) + (int)(a > b1) + (int)(a > b2)
                  + (int)(a > b3) + (int)(a > b4);
    // heaviside(0)=0: if a equals any boundary, every dist entry is 0.
    const bool eq = (a == b0) | (a == b1) | (a == b2) | (a == b3) | (a == b4);
    const float ok = eq ? 0.0f : 1.0f;

#pragma unroll
    for (int r = 0; r < 6; ++r) r6[r] = (r == cnt) ? ok : 0.0f;
    v = eq ? 0.0f : (float)cnt;
}

__global__ __launch_bounds__(256) void disc_kernel(
        const float* __restrict__ fake,
        const float* __restrict__ minb,
        const float* __restrict__ lens,
        float* __restrict__ out) {
    // Double-buffered transposed staging: 2 x (512 elem * 6 floats) = 24 KB.
    // Write side sd[h][k*BLK+t]: bank = (4t)%32 -> 8 consecutive lanes cover
    // all 32 banks exactly once: conflict-free. Read side: 3 lanes broadcast
    // per address, addresses walk banks in stride-4 groups: near-free.
    __shared__ v4f sd[2][3 * BLK];

    const int t = threadIdx.x;
    float* valbase = out + (size_t)NE * 6;

    // Per-tile input loads. d0 = column of the pair's first element (even).
    auto ldtile = [&](int tile, v2f& a, v2f& mb, v4f& L0, v4f& L1) {
        const int p = tile * BLK + t;                 // pair index
        const unsigned d0 = ((unsigned)p * 2u) % (unsigned)D;
        a  = reinterpret_cast<const v2f*>(fake)[p];
        mb = *reinterpret_cast<const v2f*>(minb + d0);     // d0 even -> 8B aligned
        L0 = reinterpret_cast<const v4f*>(lens)[d0];
        L1 = reinterpret_cast<const v4f*>(lens)[d0 + 1];
    };

    int tile = blockIdx.x;
    v2f a, mb; v4f L0, L1;
    ldtile(tile, a, mb, L0, L1);
    int h = 0;

    while (true) {
        // Prefetch next tile's inputs (HBM latency hides under this tile's
        // compute + stores). has_next is block-uniform: no divergence.
        const int ntile = tile + GRIDB;
        const bool has_next = ntile < NTILES;
        v2f an, mbn; v4f L0n, L1n;
        if (has_next) ldtile(ntile, an, mbn, L0n, L1n);

        float r0[6], r1[6], v0, v1;
        bucketize(a.x, mb.x, L0, r0, v0);
        bucketize(a.y, mb.y, L1, r1, v1);

        // val: 8B/lane, consecutive lanes -> coalesced. Issue before barrier.
        reinterpret_cast<v2f*>(valbase)[tile * BLK + t] = (v2f){v0, v1};

        // Stage 12 dist floats transposed into this iteration's LDS half.
        v4f* sh = sd[h];
        sh[0 * BLK + t] = (v4f){r0[0], r0[1], r0[2], r0[3]};
        sh[1 * BLK + t] = (v4f){r0[4], r0[5], r1[0], r1[1]};
        sh[2 * BLK + t] = (v4f){r1[2], r1[3], r1[4], r1[5]};

        __syncthreads();
        // Double buffer: reads of half h (below) are separated from the next
        // writes to half h (two iterations ahead) by the intervening barrier.

        // Tile's dist region = 768 consecutive v4f. Thread t stores logical
        // v4f j in {t, t+256, t+512}: fully coalesced 16B/lane streams.
        // Logical j belongs to source pair j/3, quarter j%3 -> sd[(j%3)*BLK+j/3].
        v4f* dp = reinterpret_cast<v4f*>(out) + (size_t)tile * (3 * BLK);
#pragma unroll
        for (int m = 0; m < 3; ++m) {
            const int j = m * BLK + t;
            const int src = j / 3;           // div by const -> mulhi+shift
            const int k = j - src * 3;
            dp[j] = sh[k * BLK + src];
        }

        if (!has_next) break;
        tile = ntile;
        h ^= 1;
        a = an; mb = mbn; L0 = L0n; L1 = L1n;
    }
}

extern "C" void kernel_launch(void* const* d_in, const int* in_sizes, int n_in,
                              void* d_out, int out_size, void* d_ws, size_t ws_size,
                              hipStream_t stream) {
    const float* fake = (const float*)d_in[0];   // [B, D]
    const float* minb = (const float*)d_in[1];   // [D]
    const float* lens = (const float*)d_in[2];   // [D, 4]
    float* out = (float*)d_out;                  // dist [B,D,6] then val [B,D]

    disc_kernel<<<GRIDB, BLK, 0, stream>>>(fake, minb, lens, out);
}

// Round 5
// 240.028 us; speedup vs baseline: 1.0352x; 1.0307x over previous
//
#include <hip/hip_runtime.h>

#define EPS 1e-4f

// Native clang vector types.
typedef float v2f __attribute__((ext_vector_type(2)));
typedef float v4f __attribute__((ext_vector_type(4)));

constexpr int B = 2048;
constexpr int D = 3706;           // even: pairs never straddle rows
constexpr int NE = B * D;         // 7,589,888 elements
constexpr int NP = NE / 2;        // 3,794,944 pairs = 14824 * 256 exactly
constexpr int BLK = 256;
constexpr int GRID = NP / BLK;    // 14824, exact (no tail)
constexpr int SROW = 257;         // padded row stride in float4s (+1 breaks
                                  // the 256*16B bank-period on the read side)

// Per-element bucketize. Boundaries are computed in the reference's exact
// fp32 order: step_k = max(L_k,0) + EPS first, then sequential cumsum adds.
__device__ __forceinline__ void bucketize(float a, float mb, v4f L,
                                          float* __restrict__ r6, float& v) {
    const float s0 = fmaxf(L.x, 0.0f) + EPS;
    const float s1 = fmaxf(L.y, 0.0f) + EPS;
    const float s2 = fmaxf(L.z, 0.0f) + EPS;
    const float s3 = fmaxf(L.w, 0.0f) + EPS;
    const float b0 = mb;
    const float b1 = b0 + s0;
    const float b2 = b1 + s1;
    const float b3 = b2 + s2;
    const float b4 = b3 + s3;

    // b is strictly increasing (steps >= EPS > 0), so {k : a > b_k} is a prefix.
    const int cnt = (int)(a > b0) + (int)(a > b1) + (int)(a > b2)
                  + (int)(a > b3) + (int)(a > b4);
    // heaviside(0)=0: if a equals any boundary, every dist entry is 0.
    const bool eq = (a == b0) | (a == b1) | (a == b2) | (a == b3) | (a == b4);
    const float ok = eq ? 0.0f : 1.0f;

#pragma unroll
    for (int r = 0; r < 6; ++r) r6[r] = (r == cnt) ? ok : 0.0f;
    v = eq ? 0.0f : (float)cnt;
}

__global__ __launch_bounds__(256) void disc_kernel(
        const float* __restrict__ fake,
        const float* __restrict__ minb,
        const float* __restrict__ lens,
        float* __restrict__ out) {
    // Padded-transposed staging: 3 rows x 257 float4 = 12,336 B (8 blocks/CU
    // by wave cap, LDS not limiting).
    // Write sd[k*SROW + t]: 64 consecutive lanes -> 64 consecutive float4s
    // per row: address-linear, full-rate (same pattern as an ideal b128 run).
    // Read sd[k*SROW + j/3] for 64 consecutive j: bank group = 4*((j%3)+(j/3))
    // mod 32 -> ~8 rows per group = the 1KB-access minimum. Near-full-rate.
    __shared__ v4f sd[3 * SROW];

    const int t = threadIdx.x;
    const int p = blockIdx.x * BLK + t;              // pair index (grid exact)
    const unsigned d0 = ((unsigned)p * 2u) % (unsigned)D;  // even column

    const v2f a  = reinterpret_cast<const v2f*>(fake)[p];
    const v2f mb = *reinterpret_cast<const v2f*>(minb + d0);  // d0 even: 8B aligned
    const v4f L0 = reinterpret_cast<const v4f*>(lens)[d0];
    const v4f L1 = reinterpret_cast<const v4f*>(lens)[d0 + 1];

    float r0[6], r1[6], v0, v1;
    bucketize(a.x, mb.x, L0, r0, v0);
    bucketize(a.y, mb.y, L1, r1, v1);

    // val: 8B/lane, consecutive lanes -> coalesced, one 512B chunk per wave.
    // Issue before the barrier so it overlaps the LDS round-trip.
    reinterpret_cast<v2f*>(out + (size_t)NE * 6)[p] = (v2f){v0, v1};

    // Thread t's quarter c is logical float4 j = 3t + c  ->  sd[c*SROW + t].
    sd[0 * SROW + t] = (v4f){r0[0], r0[1], r0[2], r0[3]};
    sd[1 * SROW + t] = (v4f){r0[4], r0[5], r1[0], r1[1]};
    sd[2 * SROW + t] = (v4f){r1[2], r1[3], r1[4], r1[5]};

    __syncthreads();

    // Block's dist region = 768 consecutive float4s. Wave w (t>>6) writes the
    // contiguous logical range [192w, 192w+192) as 3 back-to-back 1KB stores:
    // ONE sequential address stream per wave, fill-style. Logical j belongs
    // to source thread j/3, quarter j%3 -> sd[(j%3)*SROW + j/3].
    const int w    = t >> 6;
    const int lane = t & 63;
    v4f* dp = reinterpret_cast<v4f*>(out) + (size_t)blockIdx.x * (3 * BLK);
#pragma unroll
    for (int it = 0; it < 3; ++it) {
        const int j = w * 192 + it * 64 + lane;
        const int src = j / 3;                 // div by const -> mulhi+shift
        const int k = j - src * 3;
        dp[j] = sd[k * SROW + src];
    }
}

extern "C" void kernel_launch(void* const* d_in, const int* in_sizes, int n_in,
                              void* d_out, int out_size, void* d_ws, size_t ws_size,
                              hipStream_t stream) {
    const float* fake = (const float*)d_in[0];   // [B, D]
    const float* minb = (const float*)d_in[1];   // [D]
    const float* lens = (const float*)d_in[2];   // [D, 4]
    float* out = (float*)d_out;                  // dist [B,D,6] then val [B,D]

    disc_kernel<<<GRID, BLK, 0, stream>>>(fake, minb, lens, out);
}